// Round 9
// baseline (228.722 us; speedup 1.0000x reference)
//
#include <hip/hip_runtime.h>
#include <hip/hip_bf16.h>
#include <stdint.h>

// Router GEMM: out[8192,768] (fp32) = X[8192,6144] @ W[768,6144]^T
// Device buffers hold FP32 upcasts of the bf16 data (round-6 discovery).
// Round 9: latency-hiding rework at constant tiling (BM=BN=128, BK=32, SK=2):
//   - double-buffered LDS, ONE barrier per K-step (was 2)
//   - 2-deep register prefetch (pr0/pr1 banks, statically indexed 2x-unrolled
//     loop), issue-to-use ~2 compute phases -> covers L2/HBM latency
//   - corrected bank swizzle slot = k8 ^ ((row>>1)&3): ds_read quads now span
//     all 8 bank-quads (was 4-way conflicted: 128 cyc/block-step)
//   - XCD grouping + atomic split-K epilogue kept from round 8

#define M_DIM 8192
#define N_DIM 768
#define K_DIM 6144

#define BM 128
#define BN 128
#define BK 32
#define SPLITK 2
#define KSEG (K_DIM / SPLITK)    // 3072 per block
#define NT (KSEG / BK)           // 96 K-steps (even)

typedef __bf16 bf16x8 __attribute__((ext_vector_type(8)));
typedef float f32x4 __attribute__((ext_vector_type(4)));

static __device__ __forceinline__ __bf16 bf16_trunc(float f) {
    uint32_t u = __builtin_bit_cast(uint32_t, f);
    return __builtin_bit_cast(__bf16, (uint16_t)(u >> 16));  // exact on upcast data
}

static __device__ __forceinline__ bf16x8 pack_bf16x8(f32x4 a, f32x4 b) {
    bf16x8 r;
    #pragma unroll
    for (int j = 0; j < 4; ++j) {
        r[j]     = bf16_trunc(a[j]);
        r[4 + j] = bf16_trunc(b[j]);
    }
    return r;
}

__global__ __launch_bounds__(256, 3) void router_gemm_db_kernel(
    const float* __restrict__ X, const float* __restrict__ W,
    float* __restrict__ out)
{
    // double-buffered tiles: [buf][row][32k] bf16, 16B slots XOR-swizzled
    __shared__ __align__(16) __bf16 As[2][BM * BK];   // 2 x 8 KiB
    __shared__ __align__(16) __bf16 Bs[2][BN * BK];   // 2 x 8 KiB

    const int tid  = threadIdx.x;
    const int w    = tid >> 6;
    const int lane = tid & 63;

    // XCD decode: blockIdx round-robins across 8 XCDs; XCD x owns
    // {bmi 0..7} x {bn 0..5} x {ks 0..1}; bm = x*8+bmi -> X panels XCD-local.
    const int xcd  = blockIdx.x & 7;
    const int slot = blockIdx.x >> 3;      // 0..95
    const int bmi  = slot & 7;
    const int tt   = slot >> 3;            // 0..11
    const int bn   = tt % 6;
    const int ks   = tt / 6;               // 0..1
    const int bm   = xcd * 8 + bmi;        // 0..63

    const int kbase = ks * KSEG;

    const int wr = w >> 1;                 // wave row 0..1 (64 m-rows)
    const int wc = w & 1;                  // wave col 0..1 (64 n-cols)

    const int lrow = lane & 15;
    const int kg   = lane >> 4;

    // staging: unit u in [0,512) per tile; row=u>>2, k8=u&3
    const int srow = tid >> 2;             // 0..63 (also writes srow+64)
    const int sk8  = tid & 3;              // logical k-slot 0..3
    // swizzle: physical slot = k8 ^ ((row>>1)&3); rows srow and srow+64 share it
    const int wslot0 = ((sk8 ^ ((srow >> 1) & 3)) * 8);

    const float* Xg = X + (size_t)(bm * BM) * K_DIM;
    const float* Wg = W + (size_t)(bn * BN) * K_DIM;
    const float* xrow0 = Xg + (size_t)srow * K_DIM + sk8 * 8;
    const float* xrow1 = xrow0 + (size_t)64 * K_DIM;
    const float* wrow0 = Wg + (size_t)srow * K_DIM + sk8 * 8;
    const float* wrow1 = wrow0 + (size_t)64 * K_DIM;

    f32x4 pr0[8], pr1[8];

    #define ISSUE_LOADS(P, K0)                               \
        do {                                                 \
            P[0] = *(const f32x4*)(xrow0 + (K0));            \
            P[1] = *(const f32x4*)(xrow0 + (K0) + 4);        \
            P[2] = *(const f32x4*)(xrow1 + (K0));            \
            P[3] = *(const f32x4*)(xrow1 + (K0) + 4);        \
            P[4] = *(const f32x4*)(wrow0 + (K0));            \
            P[5] = *(const f32x4*)(wrow0 + (K0) + 4);        \
            P[6] = *(const f32x4*)(wrow1 + (K0));            \
            P[7] = *(const f32x4*)(wrow1 + (K0) + 4);        \
        } while (0)

    #define WRITE_LDS(BUF, P)                                                        \
        do {                                                                         \
            *(bf16x8*)(As[BUF] + srow * BK + wslot0)        = pack_bf16x8(P[0], P[1]); \
            *(bf16x8*)(As[BUF] + (srow + 64) * BK + wslot0) = pack_bf16x8(P[2], P[3]); \
            *(bf16x8*)(Bs[BUF] + srow * BK + wslot0)        = pack_bf16x8(P[4], P[5]); \
            *(bf16x8*)(Bs[BUF] + (srow + 64) * BK + wslot0) = pack_bf16x8(P[6], P[7]); \
        } while (0)

    f32x4 acc[4][4] = {};

    // frag read: physical slot = kg ^ ((row>>1)&3), row = base + f*16 + lrow
    const int rslot = (kg ^ ((lrow >> 1) & 3)) * 8;
    const int arow0 = wr * 64 + lrow;
    const int brow0 = wc * 64 + lrow;

    #define COMPUTE(BUF)                                                          \
        do {                                                                      \
            bf16x8 a[4], b[4];                                                    \
            _Pragma("unroll")                                                     \
            for (int mf = 0; mf < 4; ++mf)                                        \
                a[mf] = *(const bf16x8*)(As[BUF] + (arow0 + mf * 16) * BK + rslot); \
            _Pragma("unroll")                                                     \
            for (int nf = 0; nf < 4; ++nf)                                        \
                b[nf] = *(const bf16x8*)(Bs[BUF] + (brow0 + nf * 16) * BK + rslot); \
            _Pragma("unroll")                                                     \
            for (int mf = 0; mf < 4; ++mf)                                        \
                _Pragma("unroll")                                                 \
                for (int nf = 0; nf < 4; ++nf)                                    \
                    acc[mf][nf] = __builtin_amdgcn_mfma_f32_16x16x32_bf16(        \
                        a[mf], b[nf], acc[mf][nf], 0, 0, 0);                      \
        } while (0)

    // prologue: tile 0 staged to buf0; tile 1 loads in flight
    ISSUE_LOADS(pr0, kbase);
    WRITE_LDS(0, pr0);
    ISSUE_LOADS(pr1, kbase + BK);
    __syncthreads();

    for (int t = 0; t < NT; t += 2) {
        // even sub-step: compute buf0(t); stage buf1 <- pr1(t+1); refill pr0(t+2)
        if (t + 2 < NT) ISSUE_LOADS(pr0, kbase + (t + 2) * BK);
        COMPUTE(0);
        if (t + 1 < NT) WRITE_LDS(1, pr1);
        __syncthreads();
        // odd sub-step: compute buf1(t+1); stage buf0 <- pr0(t+2); refill pr1(t+3)
        if (t + 3 < NT) ISSUE_LOADS(pr1, kbase + (t + 3) * BK);
        COMPUTE(1);
        if (t + 2 < NT) WRITE_LDS(0, pr0);
        __syncthreads();
    }

    // epilogue: relaxed device-scope fp32 atomic add (out zeroed in launch).
    const int orow0 = bm * BM + wr * 64 + kg * 4;
    const int ocol0 = bn * BN + wc * 64 + lrow;
    #pragma unroll
    for (int mf = 0; mf < 4; ++mf)
        #pragma unroll
        for (int nf = 0; nf < 4; ++nf)
            #pragma unroll
            for (int r = 0; r < 4; ++r) {
                float* o = out + (size_t)(orow0 + mf * 16 + r) * N_DIM
                               + (ocol0 + nf * 16);
                __hip_atomic_fetch_add(o, acc[mf][nf][r],
                                       __ATOMIC_RELAXED, __HIP_MEMORY_SCOPE_AGENT);
            }

    #undef ISSUE_LOADS
    #undef WRITE_LDS
    #undef COMPUTE
}

extern "C" void kernel_launch(void* const* d_in, const int* in_sizes, int n_in,
                              void* d_out, int out_size, void* d_ws, size_t ws_size,
                              hipStream_t stream) {
    const float* X;
    const float* W;
    if (in_sizes[0] == M_DIM * K_DIM) {
        X = (const float*)d_in[0];
        W = (const float*)d_in[1];
    } else {
        X = (const float*)d_in[1];
        W = (const float*)d_in[0];
    }
    float* out = (float*)d_out;

    // zero-init for atomic accumulation (async stream op: graph-capture-safe)
    hipMemsetAsync(out, 0, (size_t)M_DIM * N_DIM * sizeof(float), stream);

    const int grid = (M_DIM / BM) * (N_DIM / BN) * SPLITK;   // 64*6*2 = 768
    hipLaunchKernelGGL(router_gemm_db_kernel, dim3(grid), dim3(256), 0, stream,
                       X, W, out);
}